// Round 1
// baseline (1031.279 us; speedup 1.0000x reference)
//
#include <hip/hip_runtime.h>
#include <math.h>

#define NNODES 50000
#define NEDGES 800000

// ---------------- CSR build ----------------

__global__ void k_init_cnt(int* __restrict__ cnt) {
    int i = blockIdx.x * 256 + threadIdx.x;
    if (i < NNODES) cnt[i] = 0;
}

__global__ void k_count(const int* __restrict__ dst, int* __restrict__ cnt) {
    int e = blockIdx.x * 256 + threadIdx.x;
    if (e < NEDGES) atomicAdd(&cnt[dst[e]], 1);
}

__global__ void k_dinv(const int* __restrict__ cnt, float* __restrict__ dinv) {
    int i = blockIdx.x * 256 + threadIdx.x;
    if (i < NNODES) dinv[i] = 1.0f / sqrtf((float)cnt[i] + 1.0f);  // +1 self loop
}

// single-block exclusive scan of cnt -> rowptr; also zeroes cnt (reused as cursor)
__global__ __launch_bounds__(1024) void k_scan(int* __restrict__ cnt, int* __restrict__ rowptr) {
    __shared__ int sums[1024];
    const int tid = threadIdx.x;
    const int chunk = (NNODES + 1023) / 1024;   // 49
    const int start = tid * chunk;
    int s = 0;
    for (int i = 0; i < chunk; ++i) {
        int idx = start + i;
        if (idx < NNODES) s += cnt[idx];
    }
    sums[tid] = s;
    __syncthreads();
    for (int off = 1; off < 1024; off <<= 1) {
        int v = 0;
        if (tid >= off) v = sums[tid - off];
        __syncthreads();
        if (tid >= off) sums[tid] += v;
        __syncthreads();
    }
    int run = (tid == 0) ? 0 : sums[tid - 1];   // exclusive base
    for (int i = 0; i < chunk; ++i) {
        int idx = start + i;
        if (idx < NNODES) {
            int v = cnt[idx];
            rowptr[idx] = run;
            run += v;
            cnt[idx] = 0;                        // reset for fill-cursor use
        }
    }
    if (tid == 1023) rowptr[NNODES] = run;       // == NEDGES
}

__global__ void k_fill(const int* __restrict__ src, const int* __restrict__ dst,
                       const int* __restrict__ rowptr, int* __restrict__ cursor,
                       const float* __restrict__ dinv,
                       int* __restrict__ col, float* __restrict__ val) {
    int e = blockIdx.x * 256 + threadIdx.x;
    if (e < NEDGES) {
        int s = src[e], d = dst[e];
        int pos = rowptr[d] + atomicAdd(&cursor[d], 1);
        col[pos] = s;
        val[pos] = dinv[s] * dinv[d];
    }
}

// ---------------- fp32 tiled GEMM ----------------
// C[M,Ncols] = A[M,K] @ W[K,Ncols] (+ bias).  256 threads, TMxTN microtile.

template<int BM, int BN, int BK, int TM, int TN>
__global__ __launch_bounds__(256) void k_gemm(const float* __restrict__ A,
                                              const float* __restrict__ W,
                                              const float* __restrict__ bias,
                                              float* __restrict__ C,
                                              int M, int Ncols, int K) {
    __shared__ __align__(16) float As[BK][BM];   // transposed A tile
    __shared__ __align__(16) float Ws[BK][BN];

    const int tid = threadIdx.x;
    const int tx = tid % (BN / TN);
    const int ty = tid / (BN / TN);
    const int m0 = blockIdx.x * BM;
    const int n0 = blockIdx.y * BN;

    float acc[TM][TN];
#pragma unroll
    for (int i = 0; i < TM; ++i)
#pragma unroll
        for (int j = 0; j < TN; ++j) acc[i][j] = 0.0f;

    constexpr int AITER = (BM * BK / 4) / 256;
    constexpr int WITER = (BK * BN / 4) / 256;

    for (int k0 = 0; k0 < K; k0 += BK) {
#pragma unroll
        for (int it = 0; it < AITER; ++it) {
            int f4 = tid + it * 256;
            int row = f4 / (BK / 4);
            int kk = (f4 % (BK / 4)) * 4;
            float4 v = make_float4(0.f, 0.f, 0.f, 0.f);
            int gr = m0 + row;
            if (gr < M) v = *(const float4*)&A[(size_t)gr * K + k0 + kk];
            As[kk + 0][row] = v.x;
            As[kk + 1][row] = v.y;
            As[kk + 2][row] = v.z;
            As[kk + 3][row] = v.w;
        }
#pragma unroll
        for (int it = 0; it < WITER; ++it) {
            int f4 = tid + it * 256;
            int kk = f4 / (BN / 4);
            int nn = (f4 % (BN / 4)) * 4;
            *(float4*)&Ws[kk][nn] = *(const float4*)&W[(size_t)(k0 + kk) * Ncols + n0 + nn];
        }
        __syncthreads();

#pragma unroll
        for (int kk = 0; kk < BK; ++kk) {
            float a[TM], b[TN];
#pragma unroll
            for (int i = 0; i < TM; i += 4)
                *(float4*)&a[i] = *(const float4*)&As[kk][ty * TM + i];
#pragma unroll
            for (int j = 0; j < TN; j += 4)
                *(float4*)&b[j] = *(const float4*)&Ws[kk][tx * TN + j];
#pragma unroll
            for (int i = 0; i < TM; ++i)
#pragma unroll
                for (int j = 0; j < TN; ++j)
                    acc[i][j] = fmaf(a[i], b[j], acc[i][j]);
        }
        __syncthreads();
    }

#pragma unroll
    for (int i = 0; i < TM; ++i) {
        int gr = m0 + ty * TM + i;
        if (gr < M) {
#pragma unroll
            for (int j = 0; j < TN; j += 4) {
                float4 v;
                v.x = acc[i][j + 0];
                v.y = acc[i][j + 1];
                v.z = acc[i][j + 2];
                v.w = acc[i][j + 3];
                if (bias != nullptr) {
                    int nb = n0 + tx * TN + j;
                    v.x += bias[nb + 0];
                    v.y += bias[nb + 1];
                    v.z += bias[nb + 2];
                    v.w += bias[nb + 3];
                }
                *(float4*)&C[(size_t)gr * Ncols + n0 + tx * TN + j] = v;
            }
        }
    }
}

// ---------------- CSR SpMM (aggregation + self loop + bias + optional relu) ----
// out[row] = sum_{e in row} H[col[e]] * val[e] + H[row]*dinv[row]^2 + bias

template<int CH, bool RELU>
__global__ __launch_bounds__(256) void k_spmm(const float* __restrict__ H,
                                              const float* __restrict__ dinv,
                                              const int* __restrict__ rowptr,
                                              const int* __restrict__ col,
                                              const float* __restrict__ val,
                                              const float* __restrict__ bias,
                                              float* __restrict__ out) {
    constexpr int CV = CH / 4;
    int t = blockIdx.x * 256 + threadIdx.x;
    int row = t / CV;
    if (row >= NNODES) return;
    int c = (t % CV) * 4;

    float dv = dinv[row];
    float s2 = dv * dv;
    float4 h = *(const float4*)&H[(size_t)row * CH + c];
    float4 b = *(const float4*)&bias[c];
    float ax = fmaf(h.x, s2, b.x);
    float ay = fmaf(h.y, s2, b.y);
    float az = fmaf(h.z, s2, b.z);
    float aw = fmaf(h.w, s2, b.w);

    int e0 = rowptr[row], e1 = rowptr[row + 1];
    for (int e = e0; e < e1; ++e) {
        int sidx = col[e];
        float w = val[e];
        float4 hv = *(const float4*)&H[(size_t)sidx * CH + c];
        ax = fmaf(hv.x, w, ax);
        ay = fmaf(hv.y, w, ay);
        az = fmaf(hv.z, w, az);
        aw = fmaf(hv.w, w, aw);
    }
    if (RELU) {
        ax = fmaxf(ax, 0.f);
        ay = fmaxf(ay, 0.f);
        az = fmaxf(az, 0.f);
        aw = fmaxf(aw, 0.f);
    }
    float4 o;
    o.x = ax; o.y = ay; o.z = az; o.w = aw;
    *(float4*)&out[(size_t)row * CH + c] = o;
}

// ---------------- launcher ----------------

extern "C" void kernel_launch(void* const* d_in, const int* in_sizes, int n_in,
                              void* d_out, int out_size, void* d_ws, size_t ws_size,
                              hipStream_t stream) {
    const float* x   = (const float*)d_in[0];
    const int*   ei  = (const int*)d_in[1];
    const float* eW1 = (const float*)d_in[2];
    const float* eb1 = (const float*)d_in[3];
    const float* eW2 = (const float*)d_in[4];
    const float* eb2 = (const float*)d_in[5];
    const float* eWf = (const float*)d_in[6];
    const float* ebf = (const float*)d_in[7];
    const float* dW1 = (const float*)d_in[8];
    const float* db1 = (const float*)d_in[9];
    const float* dW2 = (const float*)d_in[10];
    const float* db2 = (const float*)d_in[11];
    const float* dWf = (const float*)d_in[12];
    const float* dbf = (const float*)d_in[13];
    float* out = (float*)d_out;

    char* ws = (char*)d_ws;
    size_t off = 0;
    auto alloc = [&](size_t bytes) { size_t r = off; off += (bytes + 255) & ~(size_t)255; return r; };
    float* dinv   = (float*)(ws + alloc((size_t)NNODES * 4));
    int*   cnt    = (int*)  (ws + alloc((size_t)NNODES * 4));
    int*   rowptr = (int*)  (ws + alloc((size_t)(NNODES + 1) * 4));
    int*   col    = (int*)  (ws + alloc((size_t)NEDGES * 4));
    float* val    = (float*)(ws + alloc((size_t)NEDGES * 4));
    float* B1     = (float*)(ws + alloc((size_t)NNODES * 256 * 4));
    // B2 aliases the front of d_out (204.8 MB total; B2 needs 51.2 MB).
    // Its last read (A4 spmm) completes before the final GEMM writes d_out.
    float* B2 = out;

    const int* src = ei;
    const int* dst = ei + NEDGES;

    const int gN = (NNODES + 255) / 256;
    const int gE = (NEDGES + 255) / 256;

    k_init_cnt<<<gN, 256, 0, stream>>>(cnt);
    k_count<<<gE, 256, 0, stream>>>(dst, cnt);
    k_dinv<<<gN, 256, 0, stream>>>(cnt, dinv);
    k_scan<<<1, 1024, 0, stream>>>(cnt, rowptr);
    k_fill<<<gE, 256, 0, stream>>>(src, dst, rowptr, cnt, dinv, col, val);

    const int MB = (NNODES + 127) / 128;   // 391 row-blocks

    // L1: H1 = x @ eW1  [50000,128]x[128,128] -> B1
    k_gemm<128,128,16,8,8><<<dim3(MB, 1), 256, 0, stream>>>(x, eW1, nullptr, B1, NNODES, 128, 128);
    // A1 = relu(agg(H1) + eb1) -> B2
    k_spmm<128,true><<<(NNODES * 32 + 255) / 256, 256, 0, stream>>>(B1, dinv, rowptr, col, val, eb1, B2);
    // H2 = A1 @ eW2  [128->64] -> B1
    k_gemm<128,64,16,8,4><<<dim3(MB, 1), 256, 0, stream>>>(B2, eW2, nullptr, B1, NNODES, 64, 128);
    // A2 = agg(H2) + eb2 -> B2
    k_spmm<64,false><<<(NNODES * 16 + 255) / 256, 256, 0, stream>>>(B1, dinv, rowptr, col, val, eb2, B2);
    // Z = A2 @ eWf + ebf -> B1
    k_gemm<128,64,16,8,4><<<dim3(MB, 1), 256, 0, stream>>>(B2, eWf, ebf, B1, NNODES, 64, 64);
    // H3 = Z @ dW1  [64->256] -> B2
    k_gemm<128,128,16,8,8><<<dim3(MB, 2), 256, 0, stream>>>(B1, dW1, nullptr, B2, NNODES, 256, 64);
    // A3 = relu(agg(H3) + db1) -> B1
    k_spmm<256,true><<<(NNODES * 64 + 255) / 256, 256, 0, stream>>>(B2, dinv, rowptr, col, val, db1, B1);
    // H4 = A3 @ dW2  [256->128] -> B2
    k_gemm<128,128,16,8,8><<<dim3(MB, 1), 256, 0, stream>>>(B1, dW2, nullptr, B2, NNODES, 128, 256);
    // A4 = agg(H4) + db2 -> B1
    k_spmm<128,false><<<(NNODES * 32 + 255) / 256, 256, 0, stream>>>(B2, dinv, rowptr, col, val, db2, B1);
    // x_hat = A4 @ dWf + dbf -> d_out  [50000,1024]
    k_gemm<128,128,16,8,8><<<dim3(MB, 8), 256, 0, stream>>>(B1, dWf, dbf, out, NNODES, 1024, 128);
}

// Round 3
// 988.731 us; speedup vs baseline: 1.0430x; 1.0430x over previous
//
#include <hip/hip_runtime.h>
#include <math.h>

#define NNODES 50000
#define NEDGES 800000

typedef float v4f __attribute__((ext_vector_type(4)));

// ---------------- CSR build ----------------

__global__ void k_init_cnt(int* __restrict__ cnt) {
    int i = blockIdx.x * 256 + threadIdx.x;
    if (i < NNODES) cnt[i] = 0;
}

__global__ void k_count(const int* __restrict__ dst, int* __restrict__ cnt) {
    int e = blockIdx.x * 256 + threadIdx.x;
    if (e < NEDGES) atomicAdd(&cnt[dst[e]], 1);
}

__global__ void k_dinv(const int* __restrict__ cnt, float* __restrict__ dinv) {
    int i = blockIdx.x * 256 + threadIdx.x;
    if (i < NNODES) dinv[i] = 1.0f / sqrtf((float)cnt[i] + 1.0f);  // +1 self loop
}

// single-block exclusive scan of cnt -> rowptr; also zeroes cnt (reused as cursor)
__global__ __launch_bounds__(1024) void k_scan(int* __restrict__ cnt, int* __restrict__ rowptr) {
    __shared__ int sums[1024];
    const int tid = threadIdx.x;
    const int chunk = (NNODES + 1023) / 1024;   // 49
    const int start = tid * chunk;
    int s = 0;
    for (int i = 0; i < chunk; ++i) {
        int idx = start + i;
        if (idx < NNODES) s += cnt[idx];
    }
    sums[tid] = s;
    __syncthreads();
    for (int off = 1; off < 1024; off <<= 1) {
        int v = 0;
        if (tid >= off) v = sums[tid - off];
        __syncthreads();
        if (tid >= off) sums[tid] += v;
        __syncthreads();
    }
    int run = (tid == 0) ? 0 : sums[tid - 1];   // exclusive base
    for (int i = 0; i < chunk; ++i) {
        int idx = start + i;
        if (idx < NNODES) {
            int v = cnt[idx];
            rowptr[idx] = run;
            run += v;
            cnt[idx] = 0;                        // reset for fill-cursor use
        }
    }
    if (tid == 1023) rowptr[NNODES] = run;       // == NEDGES
}

__global__ void k_fill(const int* __restrict__ src, const int* __restrict__ dst,
                       const int* __restrict__ rowptr, int* __restrict__ cursor,
                       const float* __restrict__ dinv,
                       int* __restrict__ col, float* __restrict__ val) {
    int e = blockIdx.x * 256 + threadIdx.x;
    if (e < NEDGES) {
        int s = src[e], d = dst[e];
        int pos = rowptr[d] + atomicAdd(&cursor[d], 1);
        col[pos] = s;
        val[pos] = dinv[s] * dinv[d];
    }
}

// ---------------- fp32 tiled GEMM ----------------
// C[M,Ncols] = A[M,K] @ W[K,Ncols] (+ bias).  256 threads, TM x TN microtile.
// Thread's TN columns are split into TN/4 float4 chunks spaced SN=BN/(TN/4)
// apart: each b-read instruction touches a contiguous 256B LDS region ->
// 2-way bank aliasing only (free on gfx950, m136).
// Grid is 1-D MB*NB with n-block fastest so column-blocks sharing A rows are
// co-resident (A stays in L2/LLC).

template<int BM, int BN, int BK, int TM, int TN, bool NT>
__global__ __launch_bounds__(256) void k_gemm(const float* __restrict__ A,
                                              const float* __restrict__ W,
                                              const float* __restrict__ bias,
                                              float* __restrict__ C,
                                              int M, int Ncols, int K, int NB) {
    __shared__ __align__(16) float As[BK][BM];   // transposed A tile
    __shared__ __align__(16) float Ws[BK][BN];

    constexpr int CHN = TN / 4;        // float4 chunks per thread (cols)
    constexpr int SN  = BN / CHN;      // column stride between chunks
    constexpr int NTX = SN / 4;        // thread-columns (=16 for our configs)

    const int tid = threadIdx.x;
    const int tx = tid % NTX;
    const int ty = tid / NTX;
    const int bid = blockIdx.x;
    const int m0 = (bid / NB) * BM;
    const int n0 = (bid % NB) * BN;

    float acc[TM][TN];
#pragma unroll
    for (int i = 0; i < TM; ++i)
#pragma unroll
        for (int j = 0; j < TN; ++j) acc[i][j] = 0.0f;

    constexpr int AITER = (BM * BK / 4) / 256;
    constexpr int WITER = (BK * BN / 4) / 256;

    for (int k0 = 0; k0 < K; k0 += BK) {
#pragma unroll
        for (int it = 0; it < AITER; ++it) {
            int f4 = tid + it * 256;
            int row = f4 / (BK / 4);
            int kk = (f4 % (BK / 4)) * 4;
            float4 v = make_float4(0.f, 0.f, 0.f, 0.f);
            int gr = m0 + row;
            if (gr < M) v = *(const float4*)&A[(size_t)gr * K + k0 + kk];
            As[kk + 0][row] = v.x;
            As[kk + 1][row] = v.y;
            As[kk + 2][row] = v.z;
            As[kk + 3][row] = v.w;
        }
#pragma unroll
        for (int it = 0; it < WITER; ++it) {
            int f4 = tid + it * 256;
            int kk = f4 / (BN / 4);
            int nn = (f4 % (BN / 4)) * 4;
            *(float4*)&Ws[kk][nn] = *(const float4*)&W[(size_t)(k0 + kk) * Ncols + n0 + nn];
        }
        __syncthreads();

#pragma unroll
        for (int kk = 0; kk < BK; ++kk) {
            float a[TM], b[TN];
#pragma unroll
            for (int i = 0; i < TM; i += 4)
                *(float4*)&a[i] = *(const float4*)&As[kk][ty * TM + i];
#pragma unroll
            for (int c = 0; c < CHN; ++c)
                *(float4*)&b[c * 4] = *(const float4*)&Ws[kk][c * SN + tx * 4];
#pragma unroll
            for (int i = 0; i < TM; ++i)
#pragma unroll
                for (int j = 0; j < TN; ++j)
                    acc[i][j] = fmaf(a[i], b[j], acc[i][j]);
        }
        __syncthreads();
    }

#pragma unroll
    for (int i = 0; i < TM; ++i) {
        int gr = m0 + ty * TM + i;
        if (gr < M) {
#pragma unroll
            for (int c = 0; c < CHN; ++c) {
                int nb = n0 + c * SN + tx * 4;
                float4 v;
                v.x = acc[i][c * 4 + 0];
                v.y = acc[i][c * 4 + 1];
                v.z = acc[i][c * 4 + 2];
                v.w = acc[i][c * 4 + 3];
                if (bias != nullptr) {
                    v.x += bias[nb + 0];
                    v.y += bias[nb + 1];
                    v.z += bias[nb + 2];
                    v.w += bias[nb + 3];
                }
                if (NT) {
                    v4f nv;
                    nv.x = v.x; nv.y = v.y; nv.z = v.z; nv.w = v.w;
                    __builtin_nontemporal_store(nv, (v4f*)&C[(size_t)gr * Ncols + nb]);
                } else {
                    *(float4*)&C[(size_t)gr * Ncols + nb] = v;
                }
            }
        }
    }
}

// ---------------- CSR SpMM (aggregation + self loop + bias + optional relu) ----
// out[row] = sum_{e in row} H[col[e]] * val[e] + H[row]*dinv[row]^2 + bias
// Edge loop unrolled x8: batches 8 gathers in flight (latency-bound otherwise).

template<int CH, bool RELU>
__global__ __launch_bounds__(256) void k_spmm(const float* __restrict__ H,
                                              const float* __restrict__ dinv,
                                              const int* __restrict__ rowptr,
                                              const int* __restrict__ col,
                                              const float* __restrict__ val,
                                              const float* __restrict__ bias,
                                              float* __restrict__ out) {
    constexpr int CV = CH / 4;
    int t = blockIdx.x * 256 + threadIdx.x;
    int row = t / CV;
    if (row >= NNODES) return;
    int c = (t % CV) * 4;

    float dv = dinv[row];
    float s2 = dv * dv;
    float4 h = *(const float4*)&H[(size_t)row * CH + c];
    float4 b = *(const float4*)&bias[c];
    float ax = fmaf(h.x, s2, b.x);
    float ay = fmaf(h.y, s2, b.y);
    float az = fmaf(h.z, s2, b.z);
    float aw = fmaf(h.w, s2, b.w);

    const int e0 = rowptr[row], e1 = rowptr[row + 1];
    int e = e0;
    for (; e + 8 <= e1; e += 8) {
        int s[8];
        float w[8];
#pragma unroll
        for (int u = 0; u < 8; ++u) { s[u] = col[e + u]; w[u] = val[e + u]; }
        float4 hv[8];
#pragma unroll
        for (int u = 0; u < 8; ++u)
            hv[u] = *(const float4*)&H[(size_t)s[u] * CH + c];
#pragma unroll
        for (int u = 0; u < 8; ++u) {
            ax = fmaf(hv[u].x, w[u], ax);
            ay = fmaf(hv[u].y, w[u], ay);
            az = fmaf(hv[u].z, w[u], az);
            aw = fmaf(hv[u].w, w[u], aw);
        }
    }
    for (; e < e1; ++e) {
        int sidx = col[e];
        float w = val[e];
        float4 hv = *(const float4*)&H[(size_t)sidx * CH + c];
        ax = fmaf(hv.x, w, ax);
        ay = fmaf(hv.y, w, ay);
        az = fmaf(hv.z, w, az);
        aw = fmaf(hv.w, w, aw);
    }
    if (RELU) {
        ax = fmaxf(ax, 0.f);
        ay = fmaxf(ay, 0.f);
        az = fmaxf(az, 0.f);
        aw = fmaxf(aw, 0.f);
    }
    float4 o;
    o.x = ax; o.y = ay; o.z = az; o.w = aw;
    *(float4*)&out[(size_t)row * CH + c] = o;
}

// ---------------- launcher ----------------

extern "C" void kernel_launch(void* const* d_in, const int* in_sizes, int n_in,
                              void* d_out, int out_size, void* d_ws, size_t ws_size,
                              hipStream_t stream) {
    const float* x   = (const float*)d_in[0];
    const int*   ei  = (const int*)d_in[1];
    const float* eW1 = (const float*)d_in[2];
    const float* eb1 = (const float*)d_in[3];
    const float* eW2 = (const float*)d_in[4];
    const float* eb2 = (const float*)d_in[5];
    const float* eWf = (const float*)d_in[6];
    const float* ebf = (const float*)d_in[7];
    const float* dW1 = (const float*)d_in[8];
    const float* db1 = (const float*)d_in[9];
    const float* dW2 = (const float*)d_in[10];
    const float* db2 = (const float*)d_in[11];
    const float* dWf = (const float*)d_in[12];
    const float* dbf = (const float*)d_in[13];
    float* out = (float*)d_out;

    char* ws = (char*)d_ws;
    size_t off = 0;
    auto alloc = [&](size_t bytes) { size_t r = off; off += (bytes + 255) & ~(size_t)255; return r; };
    float* dinv   = (float*)(ws + alloc((size_t)NNODES * 4));
    int*   cnt    = (int*)  (ws + alloc((size_t)NNODES * 4));
    int*   rowptr = (int*)  (ws + alloc((size_t)(NNODES + 1) * 4));
    int*   col    = (int*)  (ws + alloc((size_t)NEDGES * 4));
    float* val    = (float*)(ws + alloc((size_t)NEDGES * 4));
    float* B1     = (float*)(ws + alloc((size_t)NNODES * 256 * 4));
    // B2 aliases the front of d_out (204.8 MB total; B2 needs 51.2 MB).
    // Its last read (A4 spmm) completes before the final GEMM writes d_out.
    float* B2 = out;

    const int* src = ei;
    const int* dst = ei + NEDGES;

    const int gN = (NNODES + 255) / 256;
    const int gE = (NEDGES + 255) / 256;

    k_init_cnt<<<gN, 256, 0, stream>>>(cnt);
    k_count<<<gE, 256, 0, stream>>>(dst, cnt);
    k_dinv<<<gN, 256, 0, stream>>>(cnt, dinv);
    k_scan<<<1, 1024, 0, stream>>>(cnt, rowptr);
    k_fill<<<gE, 256, 0, stream>>>(src, dst, rowptr, cnt, dinv, col, val);

    const int MB = (NNODES + 127) / 128;   // 391 row-blocks

    // L1: H1 = x @ eW1  [50000,128]x[128,128] -> B1
    k_gemm<128,128,16,8,8,false><<<MB, 256, 0, stream>>>(x, eW1, nullptr, B1, NNODES, 128, 128, 1);
    // A1 = relu(agg(H1) + eb1) -> B2
    k_spmm<128,true><<<(NNODES * 32 + 255) / 256, 256, 0, stream>>>(B1, dinv, rowptr, col, val, eb1, B2);
    // H2 = A1 @ eW2  [128->64] -> B1
    k_gemm<128,64,16,8,4,false><<<MB, 256, 0, stream>>>(B2, eW2, nullptr, B1, NNODES, 64, 128, 1);
    // A2 = agg(H2) + eb2 -> B2
    k_spmm<64,false><<<(NNODES * 16 + 255) / 256, 256, 0, stream>>>(B1, dinv, rowptr, col, val, eb2, B2);
    // Z = A2 @ eWf + ebf -> B1
    k_gemm<128,64,16,8,4,false><<<MB, 256, 0, stream>>>(B2, eWf, ebf, B1, NNODES, 64, 64, 1);
    // H3 = Z @ dW1  [64->256] -> B2
    k_gemm<128,128,16,8,8,false><<<MB * 2, 256, 0, stream>>>(B1, dW1, nullptr, B2, NNODES, 256, 64, 2);
    // A3 = relu(agg(H3) + db1) -> B1
    k_spmm<256,true><<<(NNODES * 64 + 255) / 256, 256, 0, stream>>>(B2, dinv, rowptr, col, val, db1, B1);
    // H4 = A3 @ dW2  [256->128] -> B2
    k_gemm<128,128,16,8,8,false><<<MB, 256, 0, stream>>>(B1, dW2, nullptr, B2, NNODES, 128, 256, 1);
    // A4 = agg(H4) + db2 -> B1
    k_spmm<128,false><<<(NNODES * 32 + 255) / 256, 256, 0, stream>>>(B2, dinv, rowptr, col, val, db2, B1);
    // x_hat = A4 @ dWf + dbf -> d_out  [50000,1024]  (nontemporal C stores)
    k_gemm<128,128,16,8,8,true><<<MB * 8, 256, 0, stream>>>(B1, dWf, dbf, out, NNODES, 1024, 128, 8);
}